// Round 1
// baseline (798.023 us; speedup 1.0000x reference)
//
#include <hip/hip_runtime.h>

#define NP 131072
#define C 256
#define T 16
#define BB 8
constexpr float EPS = 1e-5f;

// ---------------- ws layout (floats) ----------------
constexpr int NT       = NP * T;             // 2,097,152
constexpr int OFF_E    = 0;                  // e = exp(x_f @ Wk)  [N,T]
constexpr int OFF_DM   = NT;                 // dm' softmax       [N,T]
constexpr int OFF_Z    = 2 * NT;             // z [B,T]
constexpr int OFF_S    = OFF_Z + BB * T;     // s [B,T,C] (normalized weighted sum)
constexpr int OFF_KEYS = OFF_S + BB * T * C;
constexpr int OFF_QRS  = OFF_KEYS + BB * T * C;
constexpr int OFF_VALS = OFF_QRS + BB * T * C;
constexpr int OFF_TM   = OFF_VALS + BB * T * C;
constexpr int OFF_TP   = OFF_TM + BB * T * C;
constexpr int OFF_U    = OFF_TP + BB * T * C;
constexpr int OFF_V    = OFF_U + BB * T * C;
constexpr int OFF_CMB  = OFF_V + BB * T * C; // 5 x [C,C]: Vc,Kc,Qc,At,Ae
constexpr int OFF_DMSUM= OFF_CMB + 5 * C * C;// [B,T]
constexpr int OFF_SUMSQ= OFF_DMSUM + BB * T; // [C]
constexpr int OFF_BNA  = OFF_SUMSQ + C;      // [C]
constexpr int OFF_BNB  = OFF_BNA + C;        // [C]

__device__ inline float waveRedSum(float v) {
#pragma unroll
  for (int m = 1; m < 64; m <<= 1) v += __shfl_xor(v, m);
  return v;
}

// ---------------- K0: zero accumulators ----------------
__global__ __launch_bounds__(256) void k0_init(float* __restrict__ ws) {
  int i = blockIdx.x * 256 + threadIdx.x;
  const int n1 = BB * T + BB * T * C;   // z + s contiguous
  const int n2 = BB * T + C;            // dmsum + sumsq contiguous
  if (i < n1) ws[OFF_Z + i] = 0.f;
  else if (i < n1 + n2) ws[OFF_DMSUM + (i - n1)] = 0.f;
}

// ---------------- K1: e = exp(x_f @ Wk), z = segment_sum(e) ----------------
__global__ __launch_bounds__(256) void k1_e_z(const float* __restrict__ xf,
    const int* __restrict__ bids, const float* __restrict__ Wk,
    float* __restrict__ e, float* __restrict__ z) {
  __shared__ float wk_lds[T][C];  // wk_lds[t][c] = Wk[c*T+t]
  for (int i = threadIdx.x; i < T * C; i += 256) {
    int t = i >> 8, c = i & 255;
    wk_lds[t][c] = Wk[c * T + t];
  }
  __syncthreads();
  int n = blockIdx.x * 256 + threadIdx.x;
  float acc[T];
#pragma unroll
  for (int t = 0; t < T; ++t) acc[t] = 0.f;
  const float4* xr = (const float4*)(xf + (size_t)n * C);
  for (int c4 = 0; c4 < C / 4; ++c4) {
    float4 x = xr[c4];
#pragma unroll
    for (int t = 0; t < T; ++t) {
      float4 w = *(const float4*)&wk_lds[t][c4 * 4];
      acc[t] += x.x * w.x + x.y * w.y + x.z * w.z + x.w * w.w;
    }
  }
#pragma unroll
  for (int t = 0; t < T; ++t) acc[t] = __expf(acc[t]);
  float4* eo = (float4*)(e + (size_t)n * T);
  eo[0] = make_float4(acc[0], acc[1], acc[2], acc[3]);
  eo[1] = make_float4(acc[4], acc[5], acc[6], acc[7]);
  eo[2] = make_float4(acc[8], acc[9], acc[10], acc[11]);
  eo[3] = make_float4(acc[12], acc[13], acc[14], acc[15]);
  int b = bids[n];
  int lane = threadIdx.x & 63;
  bool uni = (__all(b == __shfl(b, 0)) != 0);
  if (uni) {
#pragma unroll
    for (int t = 0; t < T; ++t) {
      float v = waveRedSum(acc[t]);
      if (lane == 0) atomicAdd(&z[b * T + t], v);
    }
  } else {
    for (int t = 0; t < T; ++t) atomicAdd(&z[b * T + t], acc[t]);
  }
}

// ---------------- K2: s[b,t,c] = sum_n (e/z) * x_f[n,c] ----------------
constexpr int K2_PTS = 256;
__global__ __launch_bounds__(256) void k2_s(const float* __restrict__ xf,
    const int* __restrict__ bids, const float* __restrict__ e,
    const float* __restrict__ z, float* __restrict__ s) {
  __shared__ float w_lds[16][T];
  __shared__ int bid_lds[16];
  __shared__ float rz_s[BB * T];
  int tid = threadIdx.x;
  if (tid < BB * T) {
    float zz = z[tid];
    rz_s[tid] = (zz > 0.f) ? 1.f / zz : 0.f;
  }
  __syncthreads();
  int p0 = blockIdx.x * K2_PTS;
  float acc[T];
#pragma unroll
  for (int t = 0; t < T; ++t) acc[t] = 0.f;
  int cur_b = bids[p0];
  for (int g = 0; g < K2_PTS / 16; ++g) {
    int base = p0 + g * 16;
    {
      int p = tid >> 4, t = tid & 15;
      int nn = base + p;
      int bb = bids[nn];
      w_lds[p][t] = e[(size_t)nn * T + t] * rz_s[bb * T + t];
      if (tid < 16) bid_lds[tid] = bids[base + tid];
    }
    __syncthreads();
    for (int p = 0; p < 16; ++p) {
      int b = bid_lds[p];
      if (b != cur_b) {
#pragma unroll
        for (int t = 0; t < T; ++t) {
          atomicAdd(&s[((size_t)cur_b * T + t) * C + tid], acc[t]);
          acc[t] = 0.f;
        }
        cur_b = b;
      }
      float x = xf[(size_t)(base + p) * C + tid];
#pragma unroll
      for (int t = 0; t < T; ++t) acc[t] = fmaf(w_lds[p][t], x, acc[t]);
    }
    __syncthreads();
  }
#pragma unroll
  for (int t = 0; t < T; ++t)
    atomicAdd(&s[((size_t)cur_b * T + t) * C + tid], acc[t]);
}

// ---------------- K4a: combined weight mats ----------------
// mm: 0 Vc=Wv*Wq^T, 1 Kc=Wke*Wq^T, 2 Qc=Wqe*Wq^T, 3 At=Wt*Wq^T, 4 Ae=Wt*Wemb
__global__ __launch_bounds__(256) void k4a_cmb(const float* __restrict__ Wv,
    const float* __restrict__ Wke, const float* __restrict__ Wqe,
    const float* __restrict__ Wt, const float* __restrict__ Wemb,
    const float* __restrict__ Wq, float* __restrict__ cmb) {
  int mm = blockIdx.x, r = blockIdx.y;
  const float* A = (mm == 0) ? Wv : (mm == 1) ? Wke : (mm == 2) ? Wqe : Wt;
  const float* Bm = (mm == 4) ? Wemb : Wq;
  bool modeT = (mm == 4);
  __shared__ float a_lds[8 * C];
  int o0 = r * 8;
  for (int i = threadIdx.x; i < 8 * C; i += 256) a_lds[i] = A[o0 * C + i];
  __syncthreads();
  int cp = threadIdx.x;
  float acc[8];
#pragma unroll
  for (int oo = 0; oo < 8; ++oo) acc[oo] = 0.f;
  for (int c = 0; c < C; ++c) {
    float bb = modeT ? Bm[c * C + cp] : Bm[cp * C + c];
#pragma unroll
    for (int oo = 0; oo < 8; ++oo) acc[oo] = fmaf(a_lds[oo * C + c], bb, acc[oo]);
  }
  float* outp = cmb + mm * C * C;
#pragma unroll
  for (int oo = 0; oo < 8; ++oo) outp[(o0 + oo) * C + cp] = acc[oo];
}

// ---------------- K4b: keys/qrs/vals [B][T][C] ----------------
__global__ __launch_bounds__(256) void k4b_kqv(const float* __restrict__ cmb,
    const float* __restrict__ s, float* __restrict__ keys,
    float* __restrict__ qrs, float* __restrict__ vals) {
  int b = blockIdx.x, mat = blockIdx.y, q = blockIdx.z;
  const int midx0 = (mat == 0) ? 1 : (mat == 1) ? 2 : 0;
  const float* M = cmb + midx0 * C * C;
  float* outp = (mat == 0) ? keys : (mat == 1) ? qrs : vals;
  __shared__ float s_lds[T * C];
  for (int i = threadIdx.x; i < T * C; i += 256) s_lds[i] = s[(size_t)b * T * C + i];
  __syncthreads();
  int o = q * 64 + (threadIdx.x & 63);
  int tg = threadIdx.x >> 6;
  float acc[4] = {0.f, 0.f, 0.f, 0.f};
  for (int c = 0; c < C; ++c) {
    float m = M[o * C + c];
#pragma unroll
    for (int tt = 0; tt < 4; ++tt) acc[tt] = fmaf(m, s_lds[(tg * 4 + tt) * C + c], acc[tt]);
  }
#pragma unroll
  for (int tt = 0; tt < 4; ++tt)
    outp[((size_t)b * T + tg * 4 + tt) * C + o] = acc[tt];
}

// ---------------- K4c: token attention + T_middle ----------------
__global__ __launch_bounds__(256) void k4c_att(const float* __restrict__ keys,
    const float* __restrict__ qrs, const float* __restrict__ vals,
    float* __restrict__ tm) {
  int b = blockIdx.x;
  __shared__ float k_lds[T * 257];
  __shared__ float q_lds[T * 257];
  __shared__ float v_lds[T * 257];
  __shared__ float att[T * 17];
  int tid = threadIdx.x;
  for (int i = tid; i < T * C; i += 256) {
    int t = i >> 8, c = i & 255;
    k_lds[t * 257 + c] = keys[((size_t)b * T + t) * C + c];
    q_lds[t * 257 + c] = qrs[((size_t)b * T + t) * C + c];
    v_lds[t * 257 + c] = vals[((size_t)b * T + t) * C + c];
  }
  __syncthreads();
  {
    int t = tid >> 4, s2 = tid & 15;
    float acc = 0.f;
    for (int o = 0; o < C; ++o) acc = fmaf(k_lds[t * 257 + o], q_lds[s2 * 257 + o], acc);
    att[t * 17 + s2] = acc;
  }
  __syncthreads();
  if (tid < T) {
    float m = -1e30f;
    for (int s2 = 0; s2 < T; ++s2) m = fmaxf(m, att[tid * 17 + s2]);
    float sum = 0.f;
    for (int s2 = 0; s2 < T; ++s2) {
      float ee = __expf(att[tid * 17 + s2] - m);
      att[tid * 17 + s2] = ee;
      sum += ee;
    }
    float inv = 1.f / sum;
    for (int s2 = 0; s2 < T; ++s2) att[tid * 17 + s2] *= inv;
  }
  __syncthreads();
  for (int t = 0; t < T; ++t) {
    float acc = 0.f;
#pragma unroll
    for (int s2 = 0; s2 < T; ++s2) acc = fmaf(att[t * 17 + s2], v_lds[s2 * 257 + tid], acc);
    tm[((size_t)b * T + t) * C + tid] = acc;
  }
}

// ---------------- K4d: T_P = At*s + Ae*Tm ----------------
__global__ __launch_bounds__(256) void k4d_tp(const float* __restrict__ cmb,
    const float* __restrict__ s, const float* __restrict__ tm,
    float* __restrict__ tp) {
  int b = blockIdx.x, q = blockIdx.y;
  const float* At = cmb + 3 * C * C;
  const float* Ae = cmb + 4 * C * C;
  __shared__ float s_lds[T * C];
  __shared__ float tm_lds[T * C];
  for (int i = threadIdx.x; i < T * C; i += 256) {
    s_lds[i] = s[(size_t)b * T * C + i];
    tm_lds[i] = tm[(size_t)b * T * C + i];
  }
  __syncthreads();
  int o = q * 64 + (threadIdx.x & 63);
  int tg = threadIdx.x >> 6;
  float acc[4] = {0.f, 0.f, 0.f, 0.f};
  for (int c = 0; c < C; ++c) {
    float a1 = At[o * C + c], a2 = Ae[o * C + c];
#pragma unroll
    for (int tt = 0; tt < 4; ++tt) {
      int t = tg * 4 + tt;
      acc[tt] = fmaf(a1, s_lds[t * C + c], fmaf(a2, tm_lds[t * C + c], acc[tt]));
    }
  }
#pragma unroll
  for (int tt = 0; tt < 4; ++tt)
    tp[((size_t)b * T + tg * 4 + tt) * C + o] = acc[tt];
}

// ---------------- K4e: U = Wp*T_P ; V = T_P^T * Wtrans ----------------
__global__ __launch_bounds__(256) void k4e_uv(const float* __restrict__ Wp,
    const float* __restrict__ Wtrans, const float* __restrict__ tp,
    float* __restrict__ u, float* __restrict__ v) {
  int b = blockIdx.x, mat = blockIdx.y, q = blockIdx.z;
  __shared__ float tp_lds[T * C];
  for (int i = threadIdx.x; i < T * C; i += 256) tp_lds[i] = tp[(size_t)b * T * C + i];
  __syncthreads();
  int o = q * 64 + (threadIdx.x & 63);
  int tg = threadIdx.x >> 6;
  float acc[4] = {0.f, 0.f, 0.f, 0.f};
  for (int c = 0; c < C; ++c) {
    float w = mat ? Wtrans[c * C + o] : Wp[o * C + c];
#pragma unroll
    for (int tt = 0; tt < 4; ++tt) acc[tt] = fmaf(w, tp_lds[(tg * 4 + tt) * C + c], acc[tt]);
  }
  float* outp = mat ? v : u;
#pragma unroll
  for (int tt = 0; tt < 4; ++tt)
    outp[((size_t)b * T + tg * 4 + tt) * C + o] = acc[tt];
}

// ---------------- K5: dm'[n,t] = softmax_t(x_f[n]·U[b,:,t]), dmsum ----------------
__global__ __launch_bounds__(256) void k5_dm(const float* __restrict__ xf,
    const int* __restrict__ bids, const float* __restrict__ u,
    float* __restrict__ dmo, float* __restrict__ dmsum) {
  __shared__ float u_lds[T][C];
  int n = blockIdx.x * 256 + threadIdx.x;
  int b = bids[n];
  int b0 = bids[blockIdx.x * 256];
  int bL = bids[blockIdx.x * 256 + 255];
  bool fast = (b0 == bL);
  if (fast) {
    for (int i = threadIdx.x; i < T * C; i += 256) u_lds[i >> 8][i & 255] = u[(size_t)b0 * T * C + i];
    __syncthreads();
  }
  float acc[T];
#pragma unroll
  for (int t = 0; t < T; ++t) acc[t] = 0.f;
  const float4* xr = (const float4*)(xf + (size_t)n * C);
  if (fast) {
    for (int c4 = 0; c4 < C / 4; ++c4) {
      float4 x = xr[c4];
#pragma unroll
      for (int t = 0; t < T; ++t) {
        float4 w = *(const float4*)&u_lds[t][c4 * 4];
        acc[t] += x.x * w.x + x.y * w.y + x.z * w.z + x.w * w.w;
      }
    }
  } else {
    for (int c4 = 0; c4 < C / 4; ++c4) {
      float4 x = xr[c4];
#pragma unroll
      for (int t = 0; t < T; ++t) {
        float4 w = *(const float4*)&u[((size_t)b * T + t) * C + c4 * 4];
        acc[t] += x.x * w.x + x.y * w.y + x.z * w.z + x.w * w.w;
      }
    }
  }
  float m = acc[0];
#pragma unroll
  for (int t = 1; t < T; ++t) m = fmaxf(m, acc[t]);
  float ssum = 0.f;
#pragma unroll
  for (int t = 0; t < T; ++t) {
    acc[t] = __expf(acc[t] - m);
    ssum += acc[t];
  }
  float inv = 1.f / ssum;
#pragma unroll
  for (int t = 0; t < T; ++t) acc[t] *= inv;
  float4* dmop = (float4*)(dmo + (size_t)n * T);
  dmop[0] = make_float4(acc[0], acc[1], acc[2], acc[3]);
  dmop[1] = make_float4(acc[4], acc[5], acc[6], acc[7]);
  dmop[2] = make_float4(acc[8], acc[9], acc[10], acc[11]);
  dmop[3] = make_float4(acc[12], acc[13], acc[14], acc[15]);
  int lane = threadIdx.x & 63;
  bool uni = (__all(b == __shfl(b, 0)) != 0);
  if (uni) {
#pragma unroll
    for (int t = 0; t < T; ++t) {
      float vv = waveRedSum(acc[t]);
      if (lane == 0) atomicAdd(&dmsum[b * T + t], vv);
    }
  } else {
    for (int t = 0; t < T; ++t) atomicAdd(&dmsum[b * T + t], acc[t]);
  }
}

// ---------------- K6: sumsq[c] = sum_n xr[n,c]^2 ----------------
constexpr int K6_PTS = 128;
__global__ __launch_bounds__(256) void k6_sumsq(const float* __restrict__ dm,
    const int* __restrict__ bids, const float* __restrict__ v,
    float* __restrict__ sumsq) {
  __shared__ float v_lds[T * C];
  __shared__ float dm_lds[16][T];
  __shared__ int bid_lds[16];
  int tid = threadIdx.x;
  int p0 = blockIdx.x * K6_PTS;
  int cur_b = bids[p0];
  for (int i = tid; i < T * C; i += 256) v_lds[i] = v[(size_t)cur_b * T * C + i];
  __syncthreads();
  float sq = 0.f;
  for (int g = 0; g < K6_PTS / 16; ++g) {
    int base = p0 + g * 16;
    {
      int p = tid >> 4, t = tid & 15;
      dm_lds[p][t] = dm[(size_t)(base + p) * T + t];
      if (tid < 16) bid_lds[tid] = bids[base + tid];
    }
    __syncthreads();
    for (int p = 0; p < 16; ++p) {
      int b = bid_lds[p];
      if (b != cur_b) {
        __syncthreads();
        for (int i = tid; i < T * C; i += 256) v_lds[i] = v[(size_t)b * T * C + i];
        __syncthreads();
        cur_b = b;
      }
      float xr = 0.f;
#pragma unroll
      for (int t = 0; t < T; ++t) xr = fmaf(dm_lds[p][t], v_lds[t * C + tid], xr);
      sq = fmaf(xr, xr, sq);
    }
    __syncthreads();
  }
  atomicAdd(&sumsq[tid], sq);
}

// ---------------- K7: BN params ----------------
__global__ __launch_bounds__(256) void k7_bn(const float* __restrict__ dmsum,
    const float* __restrict__ sumsq, const float* __restrict__ v,
    const float* __restrict__ gamma, const float* __restrict__ beta,
    float* __restrict__ bn_a, float* __restrict__ bn_b) {
  int o = threadIdx.x;
  float mean = 0.f;
  for (int i = 0; i < BB * T; ++i) mean = fmaf(dmsum[i], v[(size_t)i * C + o], mean);
  mean *= (1.f / NP);
  float var = sumsq[o] * (1.f / NP) - mean * mean;
  float a = gamma[o] * rsqrtf(var + EPS);
  bn_a[o] = a;
  bn_b[o] = beta[o] - a * mean;
}

// ---------------- K8: out = x_f + relu(a*xr + b) ----------------
constexpr int K8_PTS = 256;
__global__ __launch_bounds__(256) void k8_out(const float* __restrict__ xf,
    const int* __restrict__ bids, const float* __restrict__ dm,
    const float* __restrict__ v, const float* __restrict__ bn_a,
    const float* __restrict__ bn_b, float* __restrict__ out) {
  __shared__ float v_lds[T * C];
  __shared__ float dm_lds[16][T];
  __shared__ int bid_lds[16];
  int tid = threadIdx.x;
  int p0 = blockIdx.x * K8_PTS;
  int cur_b = bids[p0];
  for (int i = tid; i < T * C; i += 256) v_lds[i] = v[(size_t)cur_b * T * C + i];
  __syncthreads();
  float a = bn_a[tid], bconst = bn_b[tid];
  for (int g = 0; g < K8_PTS / 16; ++g) {
    int base = p0 + g * 16;
    {
      int p = tid >> 4, t = tid & 15;
      dm_lds[p][t] = dm[(size_t)(base + p) * T + t];
      if (tid < 16) bid_lds[tid] = bids[base + tid];
    }
    __syncthreads();
    for (int p = 0; p < 16; ++p) {
      int b = bid_lds[p];
      if (b != cur_b) {
        __syncthreads();
        for (int i = tid; i < T * C; i += 256) v_lds[i] = v[(size_t)b * T * C + i];
        __syncthreads();
        cur_b = b;
      }
      float xr = 0.f;
#pragma unroll
      for (int t = 0; t < T; ++t) xr = fmaf(dm_lds[p][t], v_lds[t * C + tid], xr);
      float y = fmaf(a, xr, bconst);
      size_t idx = (size_t)(base + p) * C + tid;
      out[idx] = xf[idx] + fmaxf(y, 0.f);
    }
    __syncthreads();
  }
}

extern "C" void kernel_launch(void* const* d_in, const int* in_sizes, int n_in,
                              void* d_out, int out_size, void* d_ws, size_t ws_size,
                              hipStream_t stream) {
  const float* xf    = (const float*)d_in[0];
  const int* bids    = (const int*)d_in[1];
  const float* Wq    = (const float*)d_in[2];
  const float* Wk    = (const float*)d_in[3];
  const float* Wp    = (const float*)d_in[4];
  const float* Wv    = (const float*)d_in[5];
  const float* Wke   = (const float*)d_in[6];
  const float* Wqe   = (const float*)d_in[7];
  const float* Wemb  = (const float*)d_in[8];
  const float* Wt    = (const float*)d_in[9];
  const float* Wtr   = (const float*)d_in[10];
  const float* gamma = (const float*)d_in[11];
  const float* beta  = (const float*)d_in[12];
  float* out = (float*)d_out;
  float* ws  = (float*)d_ws;

  float* e     = ws + OFF_E;
  float* dm    = ws + OFF_DM;
  float* z     = ws + OFF_Z;
  float* s     = ws + OFF_S;
  float* keys  = ws + OFF_KEYS;
  float* qrs   = ws + OFF_QRS;
  float* vals  = ws + OFF_VALS;
  float* tm    = ws + OFF_TM;
  float* tp    = ws + OFF_TP;
  float* u     = ws + OFF_U;
  float* v     = ws + OFF_V;
  float* cmb   = ws + OFF_CMB;
  float* dmsum = ws + OFF_DMSUM;
  float* sumsq = ws + OFF_SUMSQ;
  float* bn_a  = ws + OFF_BNA;
  float* bn_b  = ws + OFF_BNB;

  const int initN = (BB * T + BB * T * C) + (BB * T + C);
  k0_init<<<(initN + 255) / 256, 256, 0, stream>>>(ws);
  k1_e_z<<<NP / 256, 256, 0, stream>>>(xf, bids, Wk, e, z);
  k2_s<<<NP / K2_PTS, 256, 0, stream>>>(xf, bids, e, z, s);
  k4a_cmb<<<dim3(5, 32), 256, 0, stream>>>(Wv, Wke, Wqe, Wt, Wemb, Wq, cmb);
  k4b_kqv<<<dim3(BB, 3, 4), 256, 0, stream>>>(cmb, s, keys, qrs, vals);
  k4c_att<<<BB, 256, 0, stream>>>(keys, qrs, vals, tm);
  k4d_tp<<<dim3(BB, 4), 256, 0, stream>>>(cmb, s, tm, tp);
  k4e_uv<<<dim3(BB, 2, 4), 256, 0, stream>>>(Wp, Wtr, tp, u, v);
  k5_dm<<<NP / 256, 256, 0, stream>>>(xf, bids, u, dm, dmsum);
  k6_sumsq<<<NP / K6_PTS, 256, 0, stream>>>(dm, bids, v, sumsq);
  k7_bn<<<1, 256, 0, stream>>>(dmsum, sumsq, v, gamma, beta, bn_a, bn_b);
  k8_out<<<NP / K8_PTS, 256, 0, stream>>>(xf, bids, dm, v, bn_a, bn_b, out);
}